// Round 13
// baseline (357.106 us; speedup 1.0000x reference)
//
#include <hip/hip_runtime.h>
#include <hip/hip_bf16.h>
#include <hip/hip_fp16.h>
#include <stdint.h>

#define C_DIM 768
#define HW 16384
#define EPSF 1e-8f
#define GPP 128            // groups (16 cols) per partition (8 partitions)

typedef __attribute__((ext_vector_type(4))) int i32x4;
typedef __attribute__((ext_vector_type(4))) float f32x4;

// ---------------- Kernel A: per-channel means (+ out init) ----------------
__global__ __launch_bounds__(256) void k_means(const float* __restrict__ x,
                                               const float* __restrict__ s,
                                               float* __restrict__ meanA,
                                               float* __restrict__ meanB,
                                               float* __restrict__ out) {
  if (blockIdx.x == 0 && threadIdx.x == 0) *out = 0.f;
  int ch = blockIdx.x;
  const float* src = (ch < C_DIM) ? (x + (size_t)ch * HW) : (s + (size_t)(ch - C_DIM) * HW);
  const float4* src4 = (const float4*)src;
  int t = threadIdx.x;
  float acc = 0.f;
  for (int i = t; i < HW / 4; i += 256) {
    float4 v = src4[i];
    acc += v.x + v.y + v.z + v.w;
  }
  __shared__ float red[256];
  red[t] = acc;
  __syncthreads();
  for (int o = 128; o > 0; o >>= 1) {
    if (t < o) red[t] += red[t + o];
    __syncthreads();
  }
  if (t == 0) {
    float m = red[0] * (1.0f / HW);
    if (ch < C_DIM) meanA[ch] = m; else meanB[ch - C_DIM] = m;
  }
}

// ---------------- Kernel S: per-position stats, float4 loads ----------------
__global__ __launch_bounds__(256) void k_stats(const float* __restrict__ x,
                                               const float* __restrict__ s,
                                               const float* __restrict__ meanA,
                                               const float* __restrict__ meanB,
                                               float* __restrict__ qsaG,
                                               float* __restrict__ qsbG,
                                               float* __restrict__ effG,
                                               float* __restrict__ invbnG,
                                               float* __restrict__ rawNA,
                                               float* __restrict__ rawNB,
                                               float* __restrict__ uG,
                                               float* __restrict__ vG,
                                               unsigned long long* __restrict__ best) {
  __shared__ float lma[C_DIM], lmb[C_DIM];
  __shared__ float part[7][4][8][4];
  int t = threadIdx.x;
  int p0 = blockIdx.x * 32;
  for (int c = t; c < C_DIM; c += 256) { lma[c] = meanA[c]; lmb[c] = meanB[c]; }
  if (t < 32) best[p0 + t] = 0ull;
  __syncthreads();

  int p4 = t & 7, cl = t >> 3;
  f32x4 a[7];
#pragma unroll
  for (int si = 0; si < 7; ++si) a[si] = (f32x4){0.f, 0.f, 0.f, 0.f};

  for (int it = 0; it < 24; ++it) {
    int c = cl + it * 32;
    f32x4 xv = *(const f32x4*)&x[(size_t)c * HW + p0 + 4 * p4];
    f32x4 sv = *(const f32x4*)&s[(size_t)c * HW + p0 + 4 * p4];
    float ma = lma[c], mb = lmb[c];
#pragma unroll
    for (int e = 0; e < 4; ++e) {
      float av = xv[e], bv = sv[e];
      float ac = av - ma, bc = bv - mb;
      a[0][e] = fmaxf(a[0][e], fabsf(ac));
      a[1][e] = fmaxf(a[1][e], fabsf(bc));
      a[2][e] += av * av;
      a[3][e] += bc * bc;
      a[4][e] += bv * bv;
      a[5][e] += ac * mb;
      a[6][e] += bc * ma;
    }
  }
#pragma unroll
  for (int off = 8; off < 64; off <<= 1) {
#pragma unroll
    for (int si = 0; si < 7; ++si)
#pragma unroll
      for (int e = 0; e < 4; ++e) {
        float o = __shfl_xor(a[si][e], off, 64);
        a[si][e] = (si < 2) ? fmaxf(a[si][e], o) : (a[si][e] + o);
      }
  }
  int w = t >> 6, l = t & 63;
  if (l < 8) {
#pragma unroll
    for (int si = 0; si < 7; ++si)
#pragma unroll
      for (int e = 0; e < 4; ++e) part[si][w][l][e] = a[si][e];
  }
  __syncthreads();
  if (t < 32) {
    int pq = t >> 2, e = t & 3;
    float ma = 0.f, mb = 0.f, sa = 0.f, sc = 0.f, sb = 0.f, uu = 0.f, vv = 0.f;
#pragma unroll
    for (int ww = 0; ww < 4; ++ww) {
      ma = fmaxf(ma, part[0][ww][pq][e]);
      mb = fmaxf(mb, part[1][ww][pq][e]);
      sa += part[2][ww][pq][e];
      sc += part[3][ww][pq][e];
      sb += part[4][ww][pq][e];
      uu += part[5][ww][pq][e];
      vv += part[6][ww][pq][e];
    }
    ma = fmaxf(ma, 1e-20f);
    mb = fmaxf(mb, 1e-20f);
    float ib = 1.0f / (sqrtf(sc + EPSF) + EPSF);
    qsaG[p0 + t] = 127.0f / ma;
    qsbG[p0 + t] = 127.0f / mb;
    effG[p0 + t] = (mb * (1.0f / 127.0f)) * ib;
    invbnG[p0 + t] = ib;
    rawNA[p0 + t] = sqrtf(sa);
    rawNB[p0 + t] = sqrtf(sb);
    uG[p0 + t] = uu;
    vG[p0 + t] = vv;
  }
}

// ---------------- Kernel Q: quantize + v_perm transpose + pack ----------------
__device__ __forceinline__ unsigned qpack4(f32x4 y) {
  unsigned r = 0;
#pragma unroll
  for (int e = 0; e < 4; ++e) {
    int q = (int)rintf(fminf(fmaxf(y[e], -127.f), 127.f));
    r |= ((unsigned)(unsigned char)(signed char)q) << (8 * e);
  }
  return r;
}

__global__ __launch_bounds__(256) void k_quant(const float* __restrict__ x,
                                               const float* __restrict__ s,
                                               const float* __restrict__ meanA,
                                               const float* __restrict__ meanB,
                                               const float* __restrict__ qsa,
                                               const float* __restrict__ qsb,
                                               signed char* __restrict__ qa,
                                               signed char* __restrict__ Bp) {
  __shared__ float lma[C_DIM], lmb[C_DIM];
  __shared__ __attribute__((aligned(8))) signed char tA8[32 * 152];
  __shared__ __attribute__((aligned(8))) signed char tB8[32 * 152];
  int t = threadIdx.x;
  int j0 = blockIdx.x * 32;
  for (int c = t; c < C_DIM; c += 256) { lma[c] = meanA[c]; lmb[c] = meanB[c]; }

  int p4 = t & 7, clq = t >> 3;
  f32x4 sa4 = *(const f32x4*)&qsa[j0 + 4 * p4];
  f32x4 sb4 = *(const f32x4*)&qsb[j0 + 4 * p4];
  int pS = t >> 3;
  int c8 = (t & 7) * 8;
  int pgS = j0 + pS;
  int gS = pgS >> 4, laneS = pgS & 15;
  __syncthreads();

  for (int it = 0; it < 6; ++it) {
    int c0 = it * 128;
    int cq = c0 + clq * 4;
    unsigned aP[4], bP[4];
#pragma unroll
    for (int k = 0; k < 4; ++k) {
      f32x4 xv = *(const f32x4*)&x[(size_t)(cq + k) * HW + j0 + 4 * p4];
      f32x4 sv = *(const f32x4*)&s[(size_t)(cq + k) * HW + j0 + 4 * p4];
      float ma = lma[cq + k], mb = lmb[cq + k];
      f32x4 ya, yb;
#pragma unroll
      for (int e = 0; e < 4; ++e) { ya[e] = (xv[e] - ma) * sa4[e]; yb[e] = (sv[e] - mb) * sb4[e]; }
      aP[k] = qpack4(ya);
      bP[k] = qpack4(yb);
    }
    unsigned tEa[4], tEb[4];
    {
      unsigned p01L = __builtin_amdgcn_perm(aP[1], aP[0], 0x05010400u);
      unsigned p23L = __builtin_amdgcn_perm(aP[3], aP[2], 0x05010400u);
      unsigned p01H = __builtin_amdgcn_perm(aP[1], aP[0], 0x07030602u);
      unsigned p23H = __builtin_amdgcn_perm(aP[3], aP[2], 0x07030602u);
      tEa[0] = __builtin_amdgcn_perm(p23L, p01L, 0x05040100u);
      tEa[1] = __builtin_amdgcn_perm(p23L, p01L, 0x07060302u);
      tEa[2] = __builtin_amdgcn_perm(p23H, p01H, 0x05040100u);
      tEa[3] = __builtin_amdgcn_perm(p23H, p01H, 0x07060302u);
      p01L = __builtin_amdgcn_perm(bP[1], bP[0], 0x05010400u);
      p23L = __builtin_amdgcn_perm(bP[3], bP[2], 0x05010400u);
      p01H = __builtin_amdgcn_perm(bP[1], bP[0], 0x07030602u);
      p23H = __builtin_amdgcn_perm(bP[3], bP[2], 0x07030602u);
      tEb[0] = __builtin_amdgcn_perm(p23L, p01L, 0x05040100u);
      tEb[1] = __builtin_amdgcn_perm(p23L, p01L, 0x07060302u);
      tEb[2] = __builtin_amdgcn_perm(p23H, p01H, 0x05040100u);
      tEb[3] = __builtin_amdgcn_perm(p23H, p01H, 0x07060302u);
    }
#pragma unroll
    for (int e = 0; e < 4; ++e) {
      *(unsigned*)&tA8[(4 * p4 + e) * 152 + clq * 4] = tEa[e];
      *(unsigned*)&tB8[(4 * p4 + e) * 152 + clq * 4] = tEb[e];
    }
    __syncthreads();
#pragma unroll
    for (int rd = 0; rd < 2; ++rd) {
      int ch8 = c8 + rd * 64;
      unsigned long long va = *(const unsigned long long*)&tA8[pS * 152 + ch8];
      *(unsigned long long*)(qa + (size_t)pgS * C_DIM + c0 + ch8) = va;
      unsigned long long vb = *(const unsigned long long*)&tB8[pS * 152 + ch8];
      int k0 = c0 + ch8;
      int sblk = k0 >> 6;
      int quad = (k0 & 63) >> 4;
      int e0 = k0 & 15;
      *(unsigned long long*)(Bp + (size_t)(gS * 12 + sblk) * 1024 + (laneS | (quad << 4)) * 16 + e0) = vb;
    }
    __syncthreads();
  }
}

// ---------------- Kernel G: i8 MFMA GEMM, 4 accumulator chains ----------------
// As R12 (1024 blocks, 8 partitions, 4-ring 52KB, vmcnt(6) stage-ahead-3) PLUS:
// each tile's 12 k-steps split into two 6-step sub-accumulators -> 4 independent
// MFMA chains. Dep distance 4 issues (~20 cy) >= MFMA latency -> matrix pipe
// fills (R12's 2 chains stalled at 46% MfmaUtil). Integer sub-sums are exact.
__device__ __forceinline__ void gl_lds16(const void* g, void* l) {
  __builtin_amdgcn_global_load_lds((const __attribute__((address_space(1))) uint32_t*)g,
                                   (__attribute__((address_space(3))) uint32_t*)l, 16, 0, 0);
}

__global__ __launch_bounds__(256, 2) void k_gemm_argmax(
    const signed char* __restrict__ qa,
    const signed char* __restrict__ Bp,
    const float* __restrict__ eff,
    unsigned long long* __restrict__ best) {
  __shared__ signed char ringS[4 * 12288];   // 48 KB
  __shared__ __half effH[2048];              // 4 KB
  int t = threadIdx.x;
  int lane = t & 63, w = t >> 6;
  int m = lane & 15, q = lane >> 4;
  int b = blockIdx.x;
  int part = b & 7;
  int rg = b >> 3;                  // 0..127
  int i0 = rg * 128;
  int g0 = part * GPP;
  int lane16 = lane * 16;
  int sW0 = (3 * w) * 1024 + lane16;

  const i32x4* qaV = (const i32x4*)qa;
  i32x4 a_res[2][12];
#pragma unroll
  for (int tm = 0; tm < 2; ++tm) {
    int row = i0 + w * 32 + tm * 16 + m;
#pragma unroll
    for (int s = 0; s < 12; ++s)
      a_res[tm][s] = qaV[(size_t)row * 48 + s * 4 + q];
  }

  {
    const signed char* ps = Bp + ((size_t)g0 * 12 + 3 * w) * 1024 + lane16;
#pragma unroll
    for (int gp = 0; gp < 3; ++gp) {
      signed char* dst = ringS + gp * 12288;
      gl_lds16(ps, dst + sW0);
      gl_lds16(ps + 1024, dst + sW0 + 1024);
      gl_lds16(ps + 2048, dst + sW0 + 2048);
      ps += 12288;
    }
  }
  for (int i = t; i < 2048; i += 256) effH[i] = __float2half(eff[(g0 << 4) + i]);
  __syncthreads();   // one-time full drain (vmcnt back to 0 outstanding)

  const signed char* srcW = Bp + ((size_t)(g0 + 3) * 12 + 3 * w) * 1024 + lane16;

  float bestv[2][4];
  int bestj[2][4];
#pragma unroll
  for (int tm = 0; tm < 2; ++tm)
#pragma unroll
    for (int r = 0; r < 4; ++r) { bestv[tm][r] = -3.0e38f; bestj[tm][r] = 0x7FFFFFFF; }

  int effOff = m;
  int jj = (g0 << 4) + m;

#define BODY(RB, VMSTR, DOSTAGE)                                                   \
  {                                                                                \
    asm volatile(VMSTR ::: "memory");                                              \
    __builtin_amdgcn_s_barrier();                                                  \
    const signed char* rb = ringS + (RB) * 12288;                                  \
    i32x4 f[12];                                                                   \
    _Pragma("unroll")                                                              \
    for (int s = 0; s < 12; ++s)                                                   \
      f[s] = *(const i32x4*)(rb + s * 1024 + lane16);                              \
    float ecur = __half2float(effH[effOff]);                                       \
    i32x4 acc0a = {0,0,0,0}, acc0b = {0,0,0,0};                                    \
    i32x4 acc1a = {0,0,0,0}, acc1b = {0,0,0,0};                                    \
    _Pragma("unroll")                                                              \
    for (int s = 0; s < 6; ++s) {                                                  \
      acc0a = __builtin_amdgcn_mfma_i32_16x16x64_i8(a_res[0][s],     f[s],     acc0a, 0, 0, 0); \
      acc1a = __builtin_amdgcn_mfma_i32_16x16x64_i8(a_res[1][s],     f[s],     acc1a, 0, 0, 0); \
      acc0b = __builtin_amdgcn_mfma_i32_16x16x64_i8(a_res[0][s + 6], f[s + 6], acc0b, 0, 0, 0); \
      acc1b = __builtin_amdgcn_mfma_i32_16x16x64_i8(a_res[1][s + 6], f[s + 6], acc1b, 0, 0, 0); \
    }                                                                              \
    if (DOSTAGE) {                                                                 \
      signed char* dst = ringS + (((RB) + 3) & 3) * 12288;                         \
      gl_lds16(srcW, dst + sW0);                                                   \
      gl_lds16(srcW + 1024, dst + sW0 + 1024);                                     \
      gl_lds16(srcW + 2048, dst + sW0 + 2048);                                     \
      srcW += 12288;                                                               \
    }                                                                              \
    _Pragma("unroll")                                                              \
    for (int r = 0; r < 4; ++r) {                                                  \
      float v0 = (float)(acc0a[r] + acc0b[r]) * ecur;                              \
      float v1 = (float)(acc1a[r] + acc1b[r]) * ecur;                              \
      if (v0 > bestv[0][r]) { bestv[0][r] = v0; bestj[0][r] = jj; }                \
      if (v1 > bestv[1][r]) { bestv[1][r] = v1; bestj[1][r] = jj; }                \
    }                                                                              \
    effOff += 16;                                                                  \
    jj += 16;                                                                      \
  }

  for (int mi = 0; mi < 31; ++mi) {   // bodies 0..123, stage groups 3..126
    BODY(0, "s_waitcnt vmcnt(6)", 1)
    BODY(1, "s_waitcnt vmcnt(6)", 1)
    BODY(2, "s_waitcnt vmcnt(6)", 1)
    BODY(3, "s_waitcnt vmcnt(6)", 1)
  }
  BODY(0, "s_waitcnt vmcnt(6)", 1)    // body 124, stages group 127
  BODY(1, "s_waitcnt vmcnt(6)", 0)    // body 125
  BODY(2, "s_waitcnt vmcnt(3)", 0)    // body 126
  BODY(3, "s_waitcnt vmcnt(0)", 0)    // body 127
#undef BODY

#pragma unroll
  for (int tm = 0; tm < 2; ++tm) {
#pragma unroll
    for (int r = 0; r < 4; ++r) {
      float bv = bestv[tm][r];
      int bj = bestj[tm][r];
#pragma unroll
      for (int off = 1; off < 16; off <<= 1) {
        float ov = __shfl_xor(bv, off, 64);
        int oj = __shfl_xor(bj, off, 64);
        if (ov > bv || (ov == bv && oj < bj)) { bv = ov; bj = oj; }
      }
      if (m == 0) {
        int i = i0 + w * 32 + tm * 16 + q * 4 + r;
        unsigned key = __float_as_uint(bv);
        key = (key & 0x80000000u) ? ~key : (key | 0x80000000u);
        unsigned long long packed =
            ((unsigned long long)key << 32) | (unsigned long long)(0xFFFFFFFFu - (unsigned)bj);
        atomicMax(&best[i], packed);
      }
    }
  }
}

// ---------------- Kernel D: final loss via analytic dot reconstruction ----------
__global__ __launch_bounds__(256) void k_loss2(const float* __restrict__ meanA,
                                               const float* __restrict__ meanB,
                                               const unsigned long long* __restrict__ best,
                                               const float* __restrict__ rawNA,
                                               const float* __restrict__ rawNB,
                                               const float* __restrict__ invbn,
                                               const float* __restrict__ qsa,
                                               const float* __restrict__ u,
                                               const float* __restrict__ v,
                                               float* __restrict__ out) {
  __shared__ float red[256];
  int t = threadIdx.x;
  float wp = 0.f;
  for (int c = t; c < C_DIM; c += 256) wp += meanA[c] * meanB[c];
  red[t] = wp;
  __syncthreads();
  for (int o = 128; o > 0; o >>= 1) {
    if (t < o) red[t] += red[t + o];
    __syncthreads();
  }
  float wdot = red[0];
  __syncthreads();

  int i = blockIdx.x * 256 + t;
  unsigned long long pk = best[i];
  unsigned key = (unsigned)(pk >> 32);
  unsigned fb = (key & 0x80000000u) ? (key & 0x7FFFFFFFu) : ~key;
  float bv = __uint_as_float(fb);
  int j = (int)(0xFFFFFFFFu - (unsigned)(pk & 0xFFFFFFFFull));
  float dotcc = bv / (invbn[j] * qsa[i]);
  float dot = dotcc + u[i] + v[j] + wdot;
  float cs = dot / ((rawNA[i] + EPSF) * (rawNB[j] + EPSF));
  red[t] = (1.0f - cs) * (1.0f / HW);
  __syncthreads();
  for (int o = 128; o > 0; o >>= 1) {
    if (t < o) red[t] += red[t + o];
    __syncthreads();
  }
  if (t == 0) atomicAdd(out, red[0]);
}

// ---------------- Launch ----------------
extern "C" void kernel_launch(void* const* d_in, const int* in_sizes, int n_in,
                              void* d_out, int out_size, void* d_ws, size_t ws_size,
                              hipStream_t stream) {
  const float* x = (const float*)d_in[0];
  const float* s = (const float*)d_in[1];
  char* ws = (char*)d_ws;
  float* meanA = (float*)(ws + 0);
  float* meanB = (float*)(ws + 4096);
  float* rawNA = (float*)(ws + 8192);
  float* rawNB = (float*)(ws + 73728);
  float* eff   = (float*)(ws + 139264);
  float* qsa   = (float*)(ws + 204800);
  float* qsb   = (float*)(ws + 270336);
  float* invbn = (float*)(ws + 335872);
  float* u     = (float*)(ws + 401408);
  float* v     = (float*)(ws + 466944);
  unsigned long long* best = (unsigned long long*)(ws + 532480);
  signed char* qa = (signed char*)(ws + 663552);
  signed char* Bp = (signed char*)(ws + 663552 + 12582912);
  float* out = (float*)d_out;

  k_means<<<2 * C_DIM, 256, 0, stream>>>(x, s, meanA, meanB, out);
  k_stats<<<HW / 32, 256, 0, stream>>>(x, s, meanA, meanB, qsa, qsb, eff, invbn, rawNA, rawNB, u, v, best);
  k_quant<<<HW / 32, 256, 0, stream>>>(x, s, meanA, meanB, qsa, qsb, qa, Bp);
  k_gemm_argmax<<<1024, 256, 0, stream>>>(qa, Bp, eff, best);
  k_loss2<<<HW / 256, 256, 0, stream>>>(meanA, meanB, best, rawNA, rawNB, invbn, qsa, u, v, out);
}

// Round 14
// 335.262 us; speedup vs baseline: 1.0652x; 1.0652x over previous
//
#include <hip/hip_runtime.h>
#include <hip/hip_bf16.h>
#include <hip/hip_fp16.h>
#include <stdint.h>

#define C_DIM 768
#define HW 16384
#define EPSF 1e-8f
#define GPQ 256            // groups (16 cols) per quarter (4 quarters, 2 XCDs each)

typedef __attribute__((ext_vector_type(4))) int i32x4;
typedef __attribute__((ext_vector_type(4))) float f32x4;

// ---------------- Kernel A: per-channel means (+ out init) ----------------
__global__ __launch_bounds__(256) void k_means(const float* __restrict__ x,
                                               const float* __restrict__ s,
                                               float* __restrict__ meanA,
                                               float* __restrict__ meanB,
                                               float* __restrict__ out) {
  if (blockIdx.x == 0 && threadIdx.x == 0) *out = 0.f;
  int ch = blockIdx.x;
  const float* src = (ch < C_DIM) ? (x + (size_t)ch * HW) : (s + (size_t)(ch - C_DIM) * HW);
  const float4* src4 = (const float4*)src;
  int t = threadIdx.x;
  float acc = 0.f;
  for (int i = t; i < HW / 4; i += 256) {
    float4 v = src4[i];
    acc += v.x + v.y + v.z + v.w;
  }
  __shared__ float red[256];
  red[t] = acc;
  __syncthreads();
  for (int o = 128; o > 0; o >>= 1) {
    if (t < o) red[t] += red[t + o];
    __syncthreads();
  }
  if (t == 0) {
    float m = red[0] * (1.0f / HW);
    if (ch < C_DIM) meanA[ch] = m; else meanB[ch - C_DIM] = m;
  }
}

// ---------------- Kernel S: per-position stats, float4 loads ----------------
__global__ __launch_bounds__(256) void k_stats(const float* __restrict__ x,
                                               const float* __restrict__ s,
                                               const float* __restrict__ meanA,
                                               const float* __restrict__ meanB,
                                               float* __restrict__ qsaG,
                                               float* __restrict__ qsbG,
                                               float* __restrict__ effG,
                                               float* __restrict__ invbnG,
                                               float* __restrict__ rawNA,
                                               float* __restrict__ rawNB,
                                               float* __restrict__ uG,
                                               float* __restrict__ vG,
                                               unsigned long long* __restrict__ best) {
  __shared__ float lma[C_DIM], lmb[C_DIM];
  __shared__ float part[7][4][8][4];
  int t = threadIdx.x;
  int p0 = blockIdx.x * 32;
  for (int c = t; c < C_DIM; c += 256) { lma[c] = meanA[c]; lmb[c] = meanB[c]; }
  if (t < 32) best[p0 + t] = 0ull;
  __syncthreads();

  int p4 = t & 7, cl = t >> 3;
  f32x4 a[7];
#pragma unroll
  for (int si = 0; si < 7; ++si) a[si] = (f32x4){0.f, 0.f, 0.f, 0.f};

  for (int it = 0; it < 24; ++it) {
    int c = cl + it * 32;
    f32x4 xv = *(const f32x4*)&x[(size_t)c * HW + p0 + 4 * p4];
    f32x4 sv = *(const f32x4*)&s[(size_t)c * HW + p0 + 4 * p4];
    float ma = lma[c], mb = lmb[c];
#pragma unroll
    for (int e = 0; e < 4; ++e) {
      float av = xv[e], bv = sv[e];
      float ac = av - ma, bc = bv - mb;
      a[0][e] = fmaxf(a[0][e], fabsf(ac));
      a[1][e] = fmaxf(a[1][e], fabsf(bc));
      a[2][e] += av * av;
      a[3][e] += bc * bc;
      a[4][e] += bv * bv;
      a[5][e] += ac * mb;
      a[6][e] += bc * ma;
    }
  }
#pragma unroll
  for (int off = 8; off < 64; off <<= 1) {
#pragma unroll
    for (int si = 0; si < 7; ++si)
#pragma unroll
      for (int e = 0; e < 4; ++e) {
        float o = __shfl_xor(a[si][e], off, 64);
        a[si][e] = (si < 2) ? fmaxf(a[si][e], o) : (a[si][e] + o);
      }
  }
  int w = t >> 6, l = t & 63;
  if (l < 8) {
#pragma unroll
    for (int si = 0; si < 7; ++si)
#pragma unroll
      for (int e = 0; e < 4; ++e) part[si][w][l][e] = a[si][e];
  }
  __syncthreads();
  if (t < 32) {
    int pq = t >> 2, e = t & 3;
    float ma = 0.f, mb = 0.f, sa = 0.f, sc = 0.f, sb = 0.f, uu = 0.f, vv = 0.f;
#pragma unroll
    for (int ww = 0; ww < 4; ++ww) {
      ma = fmaxf(ma, part[0][ww][pq][e]);
      mb = fmaxf(mb, part[1][ww][pq][e]);
      sa += part[2][ww][pq][e];
      sc += part[3][ww][pq][e];
      sb += part[4][ww][pq][e];
      uu += part[5][ww][pq][e];
      vv += part[6][ww][pq][e];
    }
    ma = fmaxf(ma, 1e-20f);
    mb = fmaxf(mb, 1e-20f);
    float ib = 1.0f / (sqrtf(sc + EPSF) + EPSF);
    qsaG[p0 + t] = 127.0f / ma;
    qsbG[p0 + t] = 127.0f / mb;
    effG[p0 + t] = (mb * (1.0f / 127.0f)) * ib;
    invbnG[p0 + t] = ib;
    rawNA[p0 + t] = sqrtf(sa);
    rawNB[p0 + t] = sqrtf(sb);
    uG[p0 + t] = uu;
    vG[p0 + t] = vv;
  }
}

// ---------------- Kernel Q: quantize + v_perm transpose + pack ----------------
__device__ __forceinline__ unsigned qpack4(f32x4 y) {
  unsigned r = 0;
#pragma unroll
  for (int e = 0; e < 4; ++e) {
    int q = (int)rintf(fminf(fmaxf(y[e], -127.f), 127.f));
    r |= ((unsigned)(unsigned char)(signed char)q) << (8 * e);
  }
  return r;
}

__global__ __launch_bounds__(256) void k_quant(const float* __restrict__ x,
                                               const float* __restrict__ s,
                                               const float* __restrict__ meanA,
                                               const float* __restrict__ meanB,
                                               const float* __restrict__ qsa,
                                               const float* __restrict__ qsb,
                                               signed char* __restrict__ qa,
                                               signed char* __restrict__ Bp) {
  __shared__ float lma[C_DIM], lmb[C_DIM];
  __shared__ __attribute__((aligned(8))) signed char tA8[32 * 152];
  __shared__ __attribute__((aligned(8))) signed char tB8[32 * 152];
  int t = threadIdx.x;
  int j0 = blockIdx.x * 32;
  for (int c = t; c < C_DIM; c += 256) { lma[c] = meanA[c]; lmb[c] = meanB[c]; }

  int p4 = t & 7, clq = t >> 3;
  f32x4 sa4 = *(const f32x4*)&qsa[j0 + 4 * p4];
  f32x4 sb4 = *(const f32x4*)&qsb[j0 + 4 * p4];
  int pS = t >> 3;
  int c8 = (t & 7) * 8;
  int pgS = j0 + pS;
  int gS = pgS >> 4, laneS = pgS & 15;
  __syncthreads();

  for (int it = 0; it < 6; ++it) {
    int c0 = it * 128;
    int cq = c0 + clq * 4;
    unsigned aP[4], bP[4];
#pragma unroll
    for (int k = 0; k < 4; ++k) {
      f32x4 xv = *(const f32x4*)&x[(size_t)(cq + k) * HW + j0 + 4 * p4];
      f32x4 sv = *(const f32x4*)&s[(size_t)(cq + k) * HW + j0 + 4 * p4];
      float ma = lma[cq + k], mb = lmb[cq + k];
      f32x4 ya, yb;
#pragma unroll
      for (int e = 0; e < 4; ++e) { ya[e] = (xv[e] - ma) * sa4[e]; yb[e] = (sv[e] - mb) * sb4[e]; }
      aP[k] = qpack4(ya);
      bP[k] = qpack4(yb);
    }
    unsigned tEa[4], tEb[4];
    {
      unsigned p01L = __builtin_amdgcn_perm(aP[1], aP[0], 0x05010400u);
      unsigned p23L = __builtin_amdgcn_perm(aP[3], aP[2], 0x05010400u);
      unsigned p01H = __builtin_amdgcn_perm(aP[1], aP[0], 0x07030602u);
      unsigned p23H = __builtin_amdgcn_perm(aP[3], aP[2], 0x07030602u);
      tEa[0] = __builtin_amdgcn_perm(p23L, p01L, 0x05040100u);
      tEa[1] = __builtin_amdgcn_perm(p23L, p01L, 0x07060302u);
      tEa[2] = __builtin_amdgcn_perm(p23H, p01H, 0x05040100u);
      tEa[3] = __builtin_amdgcn_perm(p23H, p01H, 0x07060302u);
      p01L = __builtin_amdgcn_perm(bP[1], bP[0], 0x05010400u);
      p23L = __builtin_amdgcn_perm(bP[3], bP[2], 0x05010400u);
      p01H = __builtin_amdgcn_perm(bP[1], bP[0], 0x07030602u);
      p23H = __builtin_amdgcn_perm(bP[3], bP[2], 0x07030602u);
      tEb[0] = __builtin_amdgcn_perm(p23L, p01L, 0x05040100u);
      tEb[1] = __builtin_amdgcn_perm(p23L, p01L, 0x07060302u);
      tEb[2] = __builtin_amdgcn_perm(p23H, p01H, 0x05040100u);
      tEb[3] = __builtin_amdgcn_perm(p23H, p01H, 0x07060302u);
    }
#pragma unroll
    for (int e = 0; e < 4; ++e) {
      *(unsigned*)&tA8[(4 * p4 + e) * 152 + clq * 4] = tEa[e];
      *(unsigned*)&tB8[(4 * p4 + e) * 152 + clq * 4] = tEb[e];
    }
    __syncthreads();
#pragma unroll
    for (int rd = 0; rd < 2; ++rd) {
      int ch8 = c8 + rd * 64;
      unsigned long long va = *(const unsigned long long*)&tA8[pS * 152 + ch8];
      *(unsigned long long*)(qa + (size_t)pgS * C_DIM + c0 + ch8) = va;
      unsigned long long vb = *(const unsigned long long*)&tB8[pS * 152 + ch8];
      int k0 = c0 + ch8;
      int sblk = k0 >> 6;
      int quad = (k0 & 63) >> 4;
      int e0 = k0 & 15;
      *(unsigned long long*)(Bp + (size_t)(gS * 12 + sblk) * 1024 + (laneS | (quad << 4)) * 16 + e0) = vb;
    }
    __syncthreads();
  }
}

// ---------------- Kernel G: i8 MFMA GEMM (R9-verbatim config, best measured) ----
// 512 blocks (2/CU). xcd=b&7, quarter=xcd>>1 (3MB Bp quarter shared by 2 XCDs,
// L2-resident; FETCH 37MB). Block owns 128 rows; wave owns 32 (T_m=2, 96 VGPR
// a_res). 4-deep LDS ring (48KB) + float effL (16KB) = 64KB. 3 staging loads
// per wave per body = only in-loop vmem -> s_waitcnt vmcnt(6) = stage-ahead-3
// exact. 2 MFMA chains (4-chain split regressed: R13). NEVER __launch_bounds__
// (256,4): forces 128-VGPR cap -> a_res spill (R10, 1.4GB scratch).
__device__ __forceinline__ void gl_lds16(const void* g, void* l) {
  __builtin_amdgcn_global_load_lds((const __attribute__((address_space(1))) uint32_t*)g,
                                   (__attribute__((address_space(3))) uint32_t*)l, 16, 0, 0);
}

__global__ __launch_bounds__(256, 2) void k_gemm_argmax(
    const signed char* __restrict__ qa,
    const signed char* __restrict__ Bp,
    const float* __restrict__ eff,
    unsigned long long* __restrict__ best) {
  __shared__ signed char ringS[4 * 12288];   // 48 KB
  __shared__ float effL[4096];               // 16 KB
  int t = threadIdx.x;
  int lane = t & 63, w = t >> 6;
  int m = lane & 15, q = lane >> 4;
  int b = blockIdx.x;
  int xcd = b & 7;
  int bq = xcd >> 1;
  int rg = (b >> 3) | ((xcd & 1) << 6);      // 0..127
  int i0 = rg * 128;
  int g0 = bq * GPQ;
  int lane16 = lane * 16;
  int sW0 = (3 * w) * 1024 + lane16;

  const i32x4* qaV = (const i32x4*)qa;
  i32x4 a_res[2][12];
#pragma unroll
  for (int tm = 0; tm < 2; ++tm) {
    int row = i0 + w * 32 + tm * 16 + m;
#pragma unroll
    for (int s = 0; s < 12; ++s)
      a_res[tm][s] = qaV[(size_t)row * 48 + s * 4 + q];
  }

  {
    const signed char* ps = Bp + ((size_t)g0 * 12 + 3 * w) * 1024 + lane16;
#pragma unroll
    for (int gp = 0; gp < 3; ++gp) {
      signed char* dst = ringS + gp * 12288;
      gl_lds16(ps, dst + sW0);
      gl_lds16(ps + 1024, dst + sW0 + 1024);
      gl_lds16(ps + 2048, dst + sW0 + 2048);
      ps += 12288;
    }
  }
  for (int i = t; i < 4096; i += 256) effL[i] = eff[(g0 << 4) + i];
  __syncthreads();   // one-time full drain

  const signed char* srcW = Bp + ((size_t)(g0 + 3) * 12 + 3 * w) * 1024 + lane16;

  float bestv[2][4];
  int bestj[2][4];
#pragma unroll
  for (int tm = 0; tm < 2; ++tm)
#pragma unroll
    for (int r = 0; r < 4; ++r) { bestv[tm][r] = -3.0e38f; bestj[tm][r] = 0x7FFFFFFF; }

  int effOff = m;
  int jj = (g0 << 4) + m;

#define BODY(RB, VMSTR, DOSTAGE)                                                   \
  {                                                                                \
    asm volatile(VMSTR ::: "memory");                                              \
    __builtin_amdgcn_s_barrier();                                                  \
    const signed char* rb = ringS + (RB) * 12288;                                  \
    i32x4 f[12];                                                                   \
    _Pragma("unroll")                                                              \
    for (int s = 0; s < 12; ++s)                                                   \
      f[s] = *(const i32x4*)(rb + s * 1024 + lane16);                              \
    float ecur = effL[effOff];                                                     \
    i32x4 acc0 = {0, 0, 0, 0}, acc1 = {0, 0, 0, 0};                                \
    _Pragma("unroll")                                                              \
    for (int s = 0; s < 12; ++s) {                                                 \
      acc0 = __builtin_amdgcn_mfma_i32_16x16x64_i8(a_res[0][s], f[s], acc0, 0, 0, 0); \
      acc1 = __builtin_amdgcn_mfma_i32_16x16x64_i8(a_res[1][s], f[s], acc1, 0, 0, 0); \
    }                                                                              \
    if (DOSTAGE) {                                                                 \
      signed char* dst = ringS + (((RB) + 3) & 3) * 12288;                         \
      gl_lds16(srcW, dst + sW0);                                                   \
      gl_lds16(srcW + 1024, dst + sW0 + 1024);                                     \
      gl_lds16(srcW + 2048, dst + sW0 + 2048);                                     \
      srcW += 12288;                                                               \
    }                                                                              \
    _Pragma("unroll")                                                              \
    for (int r = 0; r < 4; ++r) {                                                  \
      float v0 = (float)acc0[r] * ecur;                                            \
      float v1 = (float)acc1[r] * ecur;                                            \
      if (v0 > bestv[0][r]) { bestv[0][r] = v0; bestj[0][r] = jj; }                \
      if (v1 > bestv[1][r]) { bestv[1][r] = v1; bestj[1][r] = jj; }                \
    }                                                                              \
    effOff += 16;                                                                  \
    jj += 16;                                                                      \
  }

  for (int mi = 0; mi < 63; ++mi) {
    BODY(0, "s_waitcnt vmcnt(6)", 1)
    BODY(1, "s_waitcnt vmcnt(6)", 1)
    BODY(2, "s_waitcnt vmcnt(6)", 1)
    BODY(3, "s_waitcnt vmcnt(6)", 1)
  }
  BODY(0, "s_waitcnt vmcnt(6)", 1)   // body 252, stages group 255
  BODY(1, "s_waitcnt vmcnt(6)", 0)   // body 253
  BODY(2, "s_waitcnt vmcnt(3)", 0)   // body 254
  BODY(3, "s_waitcnt vmcnt(0)", 0)   // body 255
#undef BODY

#pragma unroll
  for (int tm = 0; tm < 2; ++tm) {
#pragma unroll
    for (int r = 0; r < 4; ++r) {
      float bv = bestv[tm][r];
      int bj = bestj[tm][r];
#pragma unroll
      for (int off = 1; off < 16; off <<= 1) {
        float ov = __shfl_xor(bv, off, 64);
        int oj = __shfl_xor(bj, off, 64);
        if (ov > bv || (ov == bv && oj < bj)) { bv = ov; bj = oj; }
      }
      if (m == 0) {
        int i = i0 + w * 32 + tm * 16 + q * 4 + r;
        unsigned key = __float_as_uint(bv);
        key = (key & 0x80000000u) ? ~key : (key | 0x80000000u);
        unsigned long long packed =
            ((unsigned long long)key << 32) | (unsigned long long)(0xFFFFFFFFu - (unsigned)bj);
        atomicMax(&best[i], packed);
      }
    }
  }
}

// ---------------- Kernel D: final loss via analytic dot reconstruction ----------
__global__ __launch_bounds__(256) void k_loss2(const float* __restrict__ meanA,
                                               const float* __restrict__ meanB,
                                               const unsigned long long* __restrict__ best,
                                               const float* __restrict__ rawNA,
                                               const float* __restrict__ rawNB,
                                               const float* __restrict__ invbn,
                                               const float* __restrict__ qsa,
                                               const float* __restrict__ u,
                                               const float* __restrict__ v,
                                               float* __restrict__ out) {
  __shared__ float red[256];
  int t = threadIdx.x;
  float wp = 0.f;
  for (int c = t; c < C_DIM; c += 256) wp += meanA[c] * meanB[c];
  red[t] = wp;
  __syncthreads();
  for (int o = 128; o > 0; o >>= 1) {
    if (t < o) red[t] += red[t + o];
    __syncthreads();
  }
  float wdot = red[0];
  __syncthreads();

  int i = blockIdx.x * 256 + t;
  unsigned long long pk = best[i];
  unsigned key = (unsigned)(pk >> 32);
  unsigned fb = (key & 0x80000000u) ? (key & 0x7FFFFFFFu) : ~key;
  float bv = __uint_as_float(fb);
  int j = (int)(0xFFFFFFFFu - (unsigned)(pk & 0xFFFFFFFFull));
  float dotcc = bv / (invbn[j] * qsa[i]);
  float dot = dotcc + u[i] + v[j] + wdot;
  float cs = dot / ((rawNA[i] + EPSF) * (rawNB[j] + EPSF));
  red[t] = (1.0f - cs) * (1.0f / HW);
  __syncthreads();
  for (int o = 128; o > 0; o >>= 1) {
    if (t < o) red[t] += red[t + o];
    __syncthreads();
  }
  if (t == 0) atomicAdd(out, red[0]);
}

// ---------------- Launch ----------------
extern "C" void kernel_launch(void* const* d_in, const int* in_sizes, int n_in,
                              void* d_out, int out_size, void* d_ws, size_t ws_size,
                              hipStream_t stream) {
  const float* x = (const float*)d_in[0];
  const float* s = (const float*)d_in[1];
  char* ws = (char*)d_ws;
  float* meanA = (float*)(ws + 0);
  float* meanB = (float*)(ws + 4096);
  float* rawNA = (float*)(ws + 8192);
  float* rawNB = (float*)(ws + 73728);
  float* eff   = (float*)(ws + 139264);
  float* qsa   = (float*)(ws + 204800);
  float* qsb   = (float*)(ws + 270336);
  float* invbn = (float*)(ws + 335872);
  float* u     = (float*)(ws + 401408);
  float* v     = (float*)(ws + 466944);
  unsigned long long* best = (unsigned long long*)(ws + 532480);
  signed char* qa = (signed char*)(ws + 663552);
  signed char* Bp = (signed char*)(ws + 663552 + 12582912);
  float* out = (float*)d_out;

  k_means<<<2 * C_DIM, 256, 0, stream>>>(x, s, meanA, meanB, out);
  k_stats<<<HW / 32, 256, 0, stream>>>(x, s, meanA, meanB, qsa, qsb, eff, invbn, rawNA, rawNB, u, v, best);
  k_quant<<<HW / 32, 256, 0, stream>>>(x, s, meanA, meanB, qsa, qsb, qa, Bp);
  k_gemm_argmax<<<512, 256, 0, stream>>>(qa, Bp, eff, best);
  k_loss2<<<HW / 256, 256, 0, stream>>>(meanA, meanB, best, rawNA, rawNB, invbn, qsa, u, v, out);
}